// Round 7
// baseline (25.824 us; speedup 1.0000x reference)
//
#include <hip/hip_runtime.h>
#include <math.h>

#define BATCH 4096
#define IMGD 192
#define HC 64
#define PADV 6
#define NBLK 512       // 2 blocks per CU
#define IPB 8          // batch items per block (NBLK * IPB == BATCH)

// padded-weight LDS layout (floats), rows padded to 12 (16B aligned):
//  per-branch block: w1@+0(9x12) w2@+108(9x12) w3@+216(15x12) b1@+396(9) b2@+405(9) b3@+414(15)
//  x-branch @0, y-branch @432; fw@864(15) fb@879 ; total 880
#define XB 0
#define YB 432
#define W1O 0
#define W2O 108
#define W3O 216
#define B1O 396
#define B2O 405
#define B3O 414
#define FWO 864
#define FBO 879

__global__ __launch_bounds__(256) void k_all(
    const float* __restrict__ x, const int* __restrict__ ij,
    const int* __restrict__ perm,
    const float* __restrict__ cw, const float* __restrict__ cb,
    const float* __restrict__ xw1, const float* __restrict__ xb1,
    const float* __restrict__ xw2, const float* __restrict__ xb2,
    const float* __restrict__ xw3, const float* __restrict__ xb3,
    const float* __restrict__ yw1, const float* __restrict__ yb1,
    const float* __restrict__ yw2, const float* __restrict__ yb2,
    const float* __restrict__ yw3, const float* __restrict__ yb3,
    const float* __restrict__ fw, const float* __restrict__ fb,
    float* __restrict__ partials,   // [0..511]=sum(pred_xy), [512..1023]=sum(exp(pred_x_y))
    int* __restrict__ counter,
    float* __restrict__ out)
{
    __shared__ __align__(16) float s[880];
    __shared__ int   pidx[IPB];
    __shared__ int   ij4[IPB * 4];       // i0, j0 (own), i0p, j0p (permuted)
    __shared__ float lpatch[IPB * 27];   // 0..8 p1, 9..17 p2, 18..26 p2s
    __shared__ float bout[3 * IPB * 15];
    __shared__ int   amlast;

    int t  = threadIdx.x;
    int b0 = blockIdx.x * IPB;

    // ---- phase A: independent loads (weights) + index chase ----
    if (t < IPB) pidx[t] = perm[b0 + t];

    for (int i = t; i < 108; i += 256) {
        int row = i / 12, col = i - row * 12;
        if (col < 9) {
            int src = row * 9 + col;
            s[XB + W1O + i] = xw1[src];  s[XB + W2O + i] = xw2[src];
            s[YB + W1O + i] = yw1[src];  s[YB + W2O + i] = yw2[src];
        }
    }
    for (int i = t; i < 180; i += 256) {
        int row = i / 12, col = i - row * 12;
        if (col < 9) {
            int src = row * 9 + col;
            s[XB + W3O + i] = xw3[src];  s[YB + W3O + i] = yw3[src];
        }
    }
    if (t >= 192) {
        int tb = t - 192;
        if (tb < 9)       { s[XB + B1O + tb] = xb1[tb];  s[XB + B2O + tb] = xb2[tb];
                            s[YB + B1O + tb] = yb1[tb];  s[YB + B2O + tb] = yb2[tb]; }
        else if (tb < 24) { int j = tb - 9;  s[XB + B3O + j] = xb3[j];  s[YB + B3O + j] = yb3[j]; }
        else if (tb < 39) { int j = tb - 24; s[FWO + j] = fw[j]; }
        else if (tb == 39){ s[FBO] = fb[0]; }
    }

    float w[9];
    #pragma unroll
    for (int i = 0; i < 9; ++i) w[i] = cw[i];   // uniform -> scalar loads
    float cbias = cb[0];

    __syncthreads();
    if (t < 2 * IPB) {
        int item = t & (IPB - 1);
        int sel  = t >> 3;                       // 0 = own, 1 = permuted
        int bb   = sel ? pidx[item] : (b0 + item);
        ij4[item * 4 + sel * 2 + 0] = ij[2 * bb];
        ij4[item * 4 + sel * 2 + 1] = ij[2 * bb + 1];
    }
    __syncthreads();

    // ---- phase B: gather, exactly one conv output per thread (t < 216) ----
    if (t < IPB * 27) {
        int item = t / 27;  int p = t - item * 27;
        int r, c, sel, slot;
        if (p < 18) { r = p / 6; c = p - r * 6; sel = 0;
                      int h = (c >= 3); slot = h * 9 + r * 3 + (c - 3 * h); }
        else        { int q = p - 18; r = q / 3; c = 3 + q - r * 3; sel = 1; slot = 18 + q; }
        int bb = sel ? pidx[item] : (b0 + item);
        int i0 = ij4[item * 4 + sel * 2], j0 = ij4[item * 4 + sel * 2 + 1];
        int rr = i0 - PADV + r;  if (rr < 0) rr += HC;
        int cc = j0 - PADV + c;  if (cc < 0) cc += HC;
        const float* xp = x + (size_t)bb * (IMGD * IMGD)
                            + (size_t)(rr * 3) * IMGD + cc * 3;
        float a0 = xp[0],        a1 = xp[1],            a2 = xp[2];
        float a3 = xp[IMGD],     a4 = xp[IMGD + 1],     a5 = xp[IMGD + 2];
        float a6 = xp[2*IMGD],   a7 = xp[2*IMGD + 1],   a8 = xp[2*IMGD + 2];
        float v = cbias + a0*w[0] + a1*w[1] + a2*w[2] + a3*w[3] + a4*w[4]
                        + a5*w[5] + a6*w[6] + a7*w[7] + a8*w[8];
        lpatch[item * 27 + slot] = v;
    }
    __syncthreads();

    // ---- phase C: MLP, 3 waves x IPB lanes (branch per wave, broadcast weights) ----
    {
        int wv = t >> 6, l = t & 63;
        if (wv < 3 && l < IPB) {
            int woff = (wv == 0) ? XB : YB;
            int ib = wv * IPB + l;
            float p[9];
            #pragma unroll
            for (int k = 0; k < 9; ++k) p[k] = lpatch[l * 27 + wv * 9 + k];

            float v[9];
            #pragma unroll
            for (int j = 0; j < 9; ++j) {
                const float4 r0 = *(const float4*)&s[woff + W1O + j * 12];
                const float4 r1 = *(const float4*)&s[woff + W1O + j * 12 + 4];
                float acc = s[woff + B1O + j]
                    + r0.x*p[0] + r0.y*p[1] + r0.z*p[2] + r0.w*p[3]
                    + r1.x*p[4] + r1.y*p[5] + r1.z*p[6] + r1.w*p[7]
                    + s[woff + W1O + j * 12 + 8] * p[8];
                v[j] = p[j] + fmaxf(acc, 0.0f);
            }
            float u[9];
            #pragma unroll
            for (int j = 0; j < 9; ++j) {
                const float4 r0 = *(const float4*)&s[woff + W2O + j * 12];
                const float4 r1 = *(const float4*)&s[woff + W2O + j * 12 + 4];
                float acc = s[woff + B2O + j]
                    + r0.x*v[0] + r0.y*v[1] + r0.z*v[2] + r0.w*v[3]
                    + r1.x*v[4] + r1.y*v[5] + r1.z*v[6] + r1.w*v[7]
                    + s[woff + W2O + j * 12 + 8] * v[8];
                u[j] = v[j] + fmaxf(acc, 0.0f);
            }
            #pragma unroll
            for (int j = 0; j < 15; ++j) {
                const float4 r0 = *(const float4*)&s[woff + W3O + j * 12];
                const float4 r1 = *(const float4*)&s[woff + W3O + j * 12 + 4];
                float acc = s[woff + B3O + j]
                    + r0.x*u[0] + r0.y*u[1] + r0.z*u[2] + r0.w*u[3]
                    + r1.x*u[4] + r1.y*u[5] + r1.z*u[6] + r1.w*u[7]
                    + s[woff + W3O + j * 12 + 8] * u[8];
                bout[ib * 15 + j] = acc;
            }
        }
    }
    __syncthreads();

    // ---- phase D: head + exp + IPB-lane reduce; t0 stores block partials ----
    if (t < IPB) {
        float fbv = s[FBO];
        float pxy = fbv, pxs = fbv;
        #pragma unroll
        for (int j = 0; j < 15; ++j) {
            float oxj  = bout[t * 15 + j];
            float oyj  = bout[(IPB + t) * 15 + j];
            float oysj = bout[(2 * IPB + t) * 15 + j];
            float fwj  = s[FWO + j];
            pxy += fmaxf(oxj + oyj,  0.0f) * fwj;
            pxs += fmaxf(oxj + oysj, 0.0f) * fwj;
        }
        float e = expf(pxs);
        #pragma unroll
        for (int o = IPB / 2; o > 0; o >>= 1) {   // shfl_down partial-wave tree: lane0 exact
            pxy += __shfl_down(pxy, o);
            e   += __shfl_down(e, o);
        }
        if (t == 0) {
            partials[blockIdx.x]        = pxy;
            partials[NBLK + blockIdx.x] = e;
        }
    }

    // ---- last-block final reduction (deterministic fixed-order sum) ----
    if (t == 0) {
        __threadfence();                          // release: partials visible device-wide
        int old = atomicAdd(counter, 1);
        amlast = (old == NBLK - 1);
    }
    __syncthreads();
    if (amlast && t < 64) {
        __threadfence();                          // acquire: invalidate stale cache
        float sx = 0.0f, se = 0.0f;
        #pragma unroll
        for (int k = 0; k < NBLK / 64; ++k) sx += partials[t + 64 * k];
        #pragma unroll
        for (int k = 0; k < NBLK / 64; ++k) se += partials[NBLK + t + 64 * k];
        #pragma unroll
        for (int o = 32; o > 0; o >>= 1) {
            sx += __shfl_down(sx, o);
            se += __shfl_down(se, o);
        }
        if (t == 0) out[0] = logf(se / (float)BATCH) - sx / (float)BATCH;
    }
}

extern "C" void kernel_launch(void* const* d_in, const int* in_sizes, int n_in,
                              void* d_out, int out_size, void* d_ws, size_t ws_size,
                              hipStream_t stream)
{
    const float* x    = (const float*)d_in[0];
    const int*   ij   = (const int*)d_in[1];
    const int*   perm = (const int*)d_in[2];
    const float* cw   = (const float*)d_in[3];
    const float* cb   = (const float*)d_in[4];
    const float* xw1  = (const float*)d_in[5];
    const float* xb1  = (const float*)d_in[6];
    const float* xw2  = (const float*)d_in[7];
    const float* xb2  = (const float*)d_in[8];
    const float* xw3  = (const float*)d_in[9];
    const float* xb3  = (const float*)d_in[10];
    const float* yw1  = (const float*)d_in[11];
    const float* yb1  = (const float*)d_in[12];
    const float* yw2  = (const float*)d_in[13];
    const float* yb2  = (const float*)d_in[14];
    const float* yw3  = (const float*)d_in[15];
    const float* yb3  = (const float*)d_in[16];
    const float* fw   = (const float*)d_in[17];
    const float* fb   = (const float*)d_in[18];

    float* partials = (float*)d_ws;               // 1024 floats
    int*   counter  = (int*)((float*)d_ws + 2 * NBLK);

    hipMemsetAsync((void*)counter, 0, 4, stream); // graph-legal, zeroes arrival counter

    k_all<<<NBLK, 256, 0, stream>>>(x, ij, perm, cw, cb,
                                    xw1, xb1, xw2, xb2, xw3, xb3,
                                    yw1, yb1, yw2, yb2, yw3, yb3,
                                    fw, fb, partials, counter, (float*)d_out);
}

// Round 9
// 12.760 us; speedup vs baseline: 2.0239x; 2.0239x over previous
//
#include <hip/hip_runtime.h>
#include <math.h>

#define BATCH 4096
#define IMGD 192
#define HC 64
#define PADV 6
#define NBLK 512       // 2 blocks per CU
#define IPB 8          // batch items per block (NBLK * IPB == BATCH)

// padded-weight LDS layout (floats), rows padded to 12 (16B aligned):
//  per-branch block: w1@+0(9x12) w2@+108(9x12) w3@+216(15x12) b1@+396(9) b2@+405(9) b3@+414(15)
//  x-branch @0, y-branch @432; fw@864(15) fb@879 ; total 880
#define XB 0
#define YB 432
#define W1O 0
#define W2O 108
#define W3O 216
#define B1O 396
#define B2O 405
#define B3O 414
#define FWO 864
#define FBO 879

__global__ __launch_bounds__(256) void k_fused(
    const float* __restrict__ x, const int* __restrict__ ij,
    const int* __restrict__ perm,
    const float* __restrict__ cw, const float* __restrict__ cb,
    const float* __restrict__ xw1, const float* __restrict__ xb1,
    const float* __restrict__ xw2, const float* __restrict__ xb2,
    const float* __restrict__ xw3, const float* __restrict__ xb3,
    const float* __restrict__ yw1, const float* __restrict__ yb1,
    const float* __restrict__ yw2, const float* __restrict__ yb2,
    const float* __restrict__ yw3, const float* __restrict__ yb3,
    const float* __restrict__ fw, const float* __restrict__ fb,
    float* __restrict__ partials)  // [0..511]=sum(pred_xy), [512..1023]=sum(exp(pred_x_y))
{
    __shared__ __align__(16) float s[880];
    __shared__ float lpatch[IPB * 27];   // 0..8 p1, 9..17 p2, 18..26 p2s
    __shared__ float bout[3 * IPB * 15];

    int t  = threadIdx.x;
    int b0 = blockIdx.x * IPB;

    // ---- gather chains issue FIRST (latency-critical, no barriers) ----
    // threads 0..143: own patches  (chain ij[b] -> pixels, 2 rounds)
    // threads 144..215: permuted   (chain perm -> ij[pb] -> pixels, 3 rounds)
    float px0, px1, px2, px3, px4, px5, px6, px7, px8;
    int   slotAddr = 0;
    bool  active = (t < IPB * 27);
    if (active) {
        int item, r, c, slot, bb;
        if (t < IPB * 18) {
            item = t / 18;  int p = t - item * 18;
            r = p / 6;  c = p - r * 6;
            int h = (c >= 3);
            slot = h * 9 + r * 3 + (c - 3 * h);
            bb = b0 + item;
        } else {
            int u = t - IPB * 18;
            item = u / 9;  int q = u - item * 9;
            r = q / 3;  c = 3 + (q - r * 3);
            slot = 18 + q;
            bb = perm[b0 + item];
        }
        int2 ij0 = ((const int2*)ij)[bb];
        int rr = ij0.x - PADV + r;  if (rr < 0) rr += HC;
        int cc = ij0.y - PADV + c;  if (cc < 0) cc += HC;
        const float* xp = x + (size_t)bb * (IMGD * IMGD)
                            + (size_t)(rr * 3) * IMGD + cc * 3;
        px0 = xp[0];        px1 = xp[1];            px2 = xp[2];
        px3 = xp[IMGD];     px4 = xp[IMGD + 1];     px5 = xp[IMGD + 2];
        px6 = xp[2*IMGD];   px7 = xp[2*IMGD + 1];   px8 = xp[2*IMGD + 2];
        slotAddr = item * 27 + slot;
    }

    // ---- weight staging (independent; overlaps the gather chains) ----
    for (int i = t; i < 108; i += 256) {
        int row = i / 12, col = i - row * 12;
        if (col < 9) {
            int src = row * 9 + col;
            s[XB + W1O + i] = xw1[src];  s[XB + W2O + i] = xw2[src];
            s[YB + W1O + i] = yw1[src];  s[YB + W2O + i] = yw2[src];
        }
    }
    for (int i = t; i < 180; i += 256) {
        int row = i / 12, col = i - row * 12;
        if (col < 9) {
            int src = row * 9 + col;
            s[XB + W3O + i] = xw3[src];  s[YB + W3O + i] = yw3[src];
        }
    }
    if (t >= 224) {
        int tb = t - 224;
        if (tb < 9)       { s[XB + B1O + tb] = xb1[tb];  s[XB + B2O + tb] = xb2[tb];
                            s[YB + B1O + tb] = yb1[tb];  s[YB + B2O + tb] = yb2[tb]; }
        else if (tb < 24) { int j = tb - 9;  s[XB + B3O + j] = xb3[j];  s[YB + B3O + j] = yb3[j]; }
        else if (tb < 31) { int j = tb - 24; s[FWO + j] = fw[j]; s[FWO + 8 + j] = fw[8 + j]; }
        else if (tb == 31){ s[FWO + 7] = fw[7]; s[FBO] = fb[0]; }
    }

    float w[9];
    #pragma unroll
    for (int i = 0; i < 9; ++i) w[i] = cw[i];   // uniform -> scalar loads
    float cbias = cb[0];

    // ---- conv FMA + LDS write ----
    if (active) {
        float v = cbias + px0*w[0] + px1*w[1] + px2*w[2] + px3*w[3] + px4*w[4]
                        + px5*w[5] + px6*w[6] + px7*w[7] + px8*w[8];
        lpatch[slotAddr] = v;
    }
    __syncthreads();

    // ---- MLP: 3 waves x IPB lanes (branch per wave, broadcast weights) ----
    {
        int wv = t >> 6, l = t & 63;
        if (wv < 3 && l < IPB) {
            int woff = (wv == 0) ? XB : YB;
            int ib = wv * IPB + l;
            float p[9];
            #pragma unroll
            for (int k = 0; k < 9; ++k) p[k] = lpatch[l * 27 + wv * 9 + k];

            float v[9];
            #pragma unroll
            for (int j = 0; j < 9; ++j) {
                const float4 r0 = *(const float4*)&s[woff + W1O + j * 12];
                const float4 r1 = *(const float4*)&s[woff + W1O + j * 12 + 4];
                float acc = s[woff + B1O + j]
                    + r0.x*p[0] + r0.y*p[1] + r0.z*p[2] + r0.w*p[3]
                    + r1.x*p[4] + r1.y*p[5] + r1.z*p[6] + r1.w*p[7]
                    + s[woff + W1O + j * 12 + 8] * p[8];
                v[j] = p[j] + fmaxf(acc, 0.0f);
            }
            float u[9];
            #pragma unroll
            for (int j = 0; j < 9; ++j) {
                const float4 r0 = *(const float4*)&s[woff + W2O + j * 12];
                const float4 r1 = *(const float4*)&s[woff + W2O + j * 12 + 4];
                float acc = s[woff + B2O + j]
                    + r0.x*v[0] + r0.y*v[1] + r0.z*v[2] + r0.w*v[3]
                    + r1.x*v[4] + r1.y*v[5] + r1.z*v[6] + r1.w*v[7]
                    + s[woff + W2O + j * 12 + 8] * v[8];
                u[j] = v[j] + fmaxf(acc, 0.0f);
            }
            #pragma unroll
            for (int j = 0; j < 15; ++j) {
                const float4 r0 = *(const float4*)&s[woff + W3O + j * 12];
                const float4 r1 = *(const float4*)&s[woff + W3O + j * 12 + 4];
                float acc = s[woff + B3O + j]
                    + r0.x*u[0] + r0.y*u[1] + r0.z*u[2] + r0.w*u[3]
                    + r1.x*u[4] + r1.y*u[5] + r1.z*u[6] + r1.w*u[7]
                    + s[woff + W3O + j * 12 + 8] * u[8];
                bout[ib * 15 + j] = acc;
            }
        }
    }
    __syncthreads();

    // ---- head + exp + IPB-lane reduce ----
    if (t < IPB) {
        float fbv = s[FBO];
        float pxy = fbv, pxs = fbv;
        #pragma unroll
        for (int j = 0; j < 15; ++j) {
            float oxj  = bout[t * 15 + j];
            float oyj  = bout[(IPB + t) * 15 + j];
            float oysj = bout[(2 * IPB + t) * 15 + j];
            float fwj  = s[FWO + j];
            pxy += fmaxf(oxj + oyj,  0.0f) * fwj;
            pxs += fmaxf(oxj + oysj, 0.0f) * fwj;
        }
        float e = expf(pxs);
        #pragma unroll
        for (int o = IPB / 2; o > 0; o >>= 1) {
            pxy += __shfl_down(pxy, o);
            e   += __shfl_down(e, o);
        }
        if (t == 0) {
            partials[blockIdx.x]        = pxy;
            partials[NBLK + blockIdx.x] = e;
        }
    }
}

// ---------------- finalize: 1 block, 256 lanes ----------------
__global__ __launch_bounds__(256) void k_final(const float* __restrict__ partials,
                                               float* __restrict__ out)
{
    __shared__ float r1[4], r2[4];
    int t = threadIdx.x;
    float sx = partials[t]        + partials[256 + t];
    float se = partials[NBLK + t] + partials[NBLK + 256 + t];
    #pragma unroll
    for (int o = 32; o > 0; o >>= 1) {
        sx += __shfl_down(sx, o);
        se += __shfl_down(se, o);
    }
    int wid = t >> 6, lane = t & 63;
    if (lane == 0) { r1[wid] = sx; r2[wid] = se; }
    __syncthreads();
    if (t == 0) {
        float S = (r1[0] + r1[1]) + (r1[2] + r1[3]);
        float E = (r2[0] + r2[1]) + (r2[2] + r2[3]);
        out[0] = logf(E / (float)BATCH) - S / (float)BATCH;
    }
}

extern "C" void kernel_launch(void* const* d_in, const int* in_sizes, int n_in,
                              void* d_out, int out_size, void* d_ws, size_t ws_size,
                              hipStream_t stream)
{
    const float* x    = (const float*)d_in[0];
    const int*   ij   = (const int*)d_in[1];
    const int*   perm = (const int*)d_in[2];
    const float* cw   = (const float*)d_in[3];
    const float* cb   = (const float*)d_in[4];
    const float* xw1  = (const float*)d_in[5];
    const float* xb1  = (const float*)d_in[6];
    const float* xw2  = (const float*)d_in[7];
    const float* xb2  = (const float*)d_in[8];
    const float* xw3  = (const float*)d_in[9];
    const float* xb3  = (const float*)d_in[10];
    const float* yw1  = (const float*)d_in[11];
    const float* yb1  = (const float*)d_in[12];
    const float* yw2  = (const float*)d_in[13];
    const float* yb2  = (const float*)d_in[14];
    const float* yw3  = (const float*)d_in[15];
    const float* yb3  = (const float*)d_in[16];
    const float* fw   = (const float*)d_in[17];
    const float* fb   = (const float*)d_in[18];

    float* partials = (float*)d_ws;   // 1024 floats, fully overwritten each launch

    k_fused<<<NBLK, 256, 0, stream>>>(x, ij, perm, cw, cb,
                                      xw1, xb1, xw2, xb2, xw3, xb3,
                                      yw1, yb1, yw2, yb2, yw3, yb3,
                                      fw, fb, partials);
    k_final<<<1, 256, 0, stream>>>(partials, (float*)d_out);
}

// Round 10
// 12.177 us; speedup vs baseline: 2.1206x; 1.0478x over previous
//
#include <hip/hip_runtime.h>
#include <math.h>

#define BATCH 4096
#define IMGD 192
#define HC 64
#define PADV 6
#define NBLK2 256      // one block per CU
#define IPB 16         // batch items per block

// padded-weight LDS layout (floats), rows padded to 12 (16B aligned):
//  per-branch block: w1@+0(9x12) w2@+108(9x12) w3@+216(15x12) b1@+396(9) b2@+405(9) b3@+414(15)
//  x-branch @0, y-branch @432; fw@864(15) fb@879 ; total 880
#define XB 0
#define YB 432
#define W1O 0
#define W2O 108
#define W3O 216
#define B1O 396
#define B2O 405
#define B3O 414
#define FWO 864
#define FBO 879

__global__ __launch_bounds__(256) void k_fused(
    const float* __restrict__ x, const int* __restrict__ ij,
    const int* __restrict__ perm,
    const float* __restrict__ cw, const float* __restrict__ cb,
    const float* __restrict__ xw1, const float* __restrict__ xb1,
    const float* __restrict__ xw2, const float* __restrict__ xb2,
    const float* __restrict__ xw3, const float* __restrict__ xb3,
    const float* __restrict__ yw1, const float* __restrict__ yb1,
    const float* __restrict__ yw2, const float* __restrict__ yb2,
    const float* __restrict__ yw3, const float* __restrict__ yb3,
    const float* __restrict__ fw, const float* __restrict__ fb,
    float* __restrict__ partials)  // [0..255]=sum(pred_xy), [256..511]=sum(exp(pred_x_y))
{
    __shared__ __align__(16) float s[880];
    __shared__ int   pidx[IPB];
    __shared__ int2  ij2[2 * IPB];       // [0..15] own (i0,j0), [16..31] permuted
    __shared__ float lpatch[IPB * 27];   // 0..8 p1, 9..17 p2, 18..26 p2s
    __shared__ float bout[48 * 15];

    int t  = threadIdx.x;
    int b0 = blockIdx.x * IPB;

    // ---- dependent index chains FIRST, in-register, split across waves ----
    if (t < IPB) {                        // wave 0: perm -> ij[pb] (the 2-round chain)
        int pb  = perm[b0 + t];
        pidx[t] = pb;
        ij2[IPB + t] = ((const int2*)ij)[pb];
    } else if (t >= 64 && t < 64 + IPB) { // wave 1: own ij (1 round, parallel)
        int item = t - 64;
        ij2[item] = ((const int2*)ij)[b0 + item];
    }

    // ---- weight staging (independent loads; overlap the chains) ----
    for (int i = t; i < 108; i += 256) {
        int row = i / 12, col = i - row * 12;
        if (col < 9) {
            int src = row * 9 + col;
            s[XB + W1O + i] = xw1[src];  s[XB + W2O + i] = xw2[src];
            s[YB + W1O + i] = yw1[src];  s[YB + W2O + i] = yw2[src];
        }
    }
    for (int i = t; i < 180; i += 256) {
        int row = i / 12, col = i - row * 12;
        if (col < 9) {
            int src = row * 9 + col;
            s[XB + W3O + i] = xw3[src];  s[YB + W3O + i] = yw3[src];
        }
    }
    if (t >= 192) {
        int tb = t - 192;
        if (tb < 9)       { s[XB + B1O + tb] = xb1[tb];  s[XB + B2O + tb] = xb2[tb];
                            s[YB + B1O + tb] = yb1[tb];  s[YB + B2O + tb] = yb2[tb]; }
        else if (tb < 24) { int j = tb - 9;  s[XB + B3O + j] = xb3[j];  s[YB + B3O + j] = yb3[j]; }
        else if (tb < 39) { int j = tb - 24; s[FWO + j] = fw[j]; }
        else if (tb == 39){ s[FBO] = fb[0]; }
    }

    float w[9];
    #pragma unroll
    for (int i = 0; i < 9; ++i) w[i] = cw[i];   // uniform -> scalar loads
    float cbias = cb[0];
    __syncthreads();                     // single barrier before gather

    // ---- gather: 2 conv outputs per thread, indices LDS-resident ----
    {
        int idxA = t;
        int itemA = idxA / 27;  int pA = idxA - itemA * 27;
        int rA, cA, selA, slotA;
        if (pA < 18) { rA = pA / 6; cA = pA - rA * 6; selA = 0;
                       int h = (cA >= 3); slotA = h * 9 + rA * 3 + (cA - 3 * h); }
        else         { int q = pA - 18; rA = q / 3; cA = 3 + q - rA * 3; selA = 1; slotA = 18 + q; }
        int bbA = selA ? pidx[itemA] : (b0 + itemA);
        int2 ijA = ij2[selA * IPB + itemA];
        int rrA = ijA.x - PADV + rA;  if (rrA < 0) rrA += HC;
        int ccA = ijA.y - PADV + cA;  if (ccA < 0) ccA += HC;
        const float* pa = x + (size_t)bbA * (IMGD * IMGD) + (size_t)(rrA * 3) * IMGD + ccA * 3;

        bool hasB = (t < 176);
        int idxB = t + 256;
        int itemB = idxB / 27;  int pB = idxB - itemB * 27;
        int rB, cB, selB, slotB;
        if (pB < 18) { rB = pB / 6; cB = pB - rB * 6; selB = 0;
                       int h = (cB >= 3); slotB = h * 9 + rB * 3 + (cB - 3 * h); }
        else         { int q = pB - 18; rB = q / 3; cB = 3 + q - rB * 3; selB = 1; slotB = 18 + q; }
        itemB = hasB ? itemB : 0;
        int bbB = selB ? pidx[itemB] : (b0 + itemB);
        int2 ijB = ij2[selB * IPB + itemB];
        int rrB = ijB.x - PADV + rB;  if (rrB < 0) rrB += HC;
        int ccB = ijB.y - PADV + cB;  if (ccB < 0) ccB += HC;
        const float* pb = hasB ? (x + (size_t)bbB * (IMGD * IMGD) + (size_t)(rrB * 3) * IMGD + ccB * 3)
                               : pa;

        float a0 = pa[0],          a1 = pa[1],            a2 = pa[2];
        float a3 = pa[IMGD],       a4 = pa[IMGD + 1],     a5 = pa[IMGD + 2];
        float a6 = pa[2 * IMGD],   a7 = pa[2 * IMGD + 1], a8 = pa[2 * IMGD + 2];
        float e0 = pb[0],          e1 = pb[1],            e2 = pb[2];
        float e3 = pb[IMGD],       e4 = pb[IMGD + 1],     e5 = pb[IMGD + 2];
        float e6 = pb[2 * IMGD],   e7 = pb[2 * IMGD + 1], e8 = pb[2 * IMGD + 2];

        float vA = cbias + a0*w[0] + a1*w[1] + a2*w[2] + a3*w[3] + a4*w[4]
                         + a5*w[5] + a6*w[6] + a7*w[7] + a8*w[8];
        lpatch[itemA * 27 + slotA] = vA;
        if (hasB) {
            float vB = cbias + e0*w[0] + e1*w[1] + e2*w[2] + e3*w[3] + e4*w[4]
                             + e5*w[5] + e6*w[6] + e7*w[7] + e8*w[8];
            lpatch[itemB * 27 + slotB] = vB;
        }
    }
    __syncthreads();

    // ---- MLP: 3 waves x 16 lanes (branch per wave, broadcast weights) ----
    {
        int wv = t >> 6, l = t & 63;
        if (wv < 3 && l < 16) {
            int woff = (wv == 0) ? XB : YB;
            int ib = wv * 16 + l;
            float p[9];
            #pragma unroll
            for (int k = 0; k < 9; ++k) p[k] = lpatch[l * 27 + wv * 9 + k];

            float v[9];
            #pragma unroll
            for (int j = 0; j < 9; ++j) {
                const float4 r0 = *(const float4*)&s[woff + W1O + j * 12];
                const float4 r1 = *(const float4*)&s[woff + W1O + j * 12 + 4];
                float acc = s[woff + B1O + j]
                    + r0.x*p[0] + r0.y*p[1] + r0.z*p[2] + r0.w*p[3]
                    + r1.x*p[4] + r1.y*p[5] + r1.z*p[6] + r1.w*p[7]
                    + s[woff + W1O + j * 12 + 8] * p[8];
                v[j] = p[j] + fmaxf(acc, 0.0f);
            }
            float u[9];
            #pragma unroll
            for (int j = 0; j < 9; ++j) {
                const float4 r0 = *(const float4*)&s[woff + W2O + j * 12];
                const float4 r1 = *(const float4*)&s[woff + W2O + j * 12 + 4];
                float acc = s[woff + B2O + j]
                    + r0.x*v[0] + r0.y*v[1] + r0.z*v[2] + r0.w*v[3]
                    + r1.x*v[4] + r1.y*v[5] + r1.z*v[6] + r1.w*v[7]
                    + s[woff + W2O + j * 12 + 8] * v[8];
                u[j] = v[j] + fmaxf(acc, 0.0f);
            }
            #pragma unroll
            for (int j = 0; j < 15; ++j) {
                const float4 r0 = *(const float4*)&s[woff + W3O + j * 12];
                const float4 r1 = *(const float4*)&s[woff + W3O + j * 12 + 4];
                float acc = s[woff + B3O + j]
                    + r0.x*u[0] + r0.y*u[1] + r0.z*u[2] + r0.w*u[3]
                    + r1.x*u[4] + r1.y*u[5] + r1.z*u[6] + r1.w*u[7]
                    + s[woff + W3O + j * 12 + 8] * u[8];
                bout[ib * 15 + j] = acc;
            }
        }
    }
    __syncthreads();

    // ---- head + exp + 16-lane reduce ----
    if (t < IPB) {
        float fbv = s[FBO];
        float pxy = fbv, pxs = fbv;
        #pragma unroll
        for (int j = 0; j < 15; ++j) {
            float oxj  = bout[t * 15 + j];
            float oyj  = bout[(16 + t) * 15 + j];
            float oysj = bout[(32 + t) * 15 + j];
            float fwj  = s[FWO + j];
            pxy += fmaxf(oxj + oyj,  0.0f) * fwj;
            pxs += fmaxf(oxj + oysj, 0.0f) * fwj;
        }
        float e = expf(pxs);
        #pragma unroll
        for (int o = 8; o > 0; o >>= 1) {
            pxy += __shfl_down(pxy, o);
            e   += __shfl_down(e, o);
        }
        if (t == 0) {
            partials[blockIdx.x]         = pxy;
            partials[NBLK2 + blockIdx.x] = e;
        }
    }
}

// ---------------- finalize: 1 block, 256 lanes ----------------
__global__ __launch_bounds__(256) void k_final(const float* __restrict__ partials,
                                               float* __restrict__ out)
{
    __shared__ float r1[4], r2[4];
    int t = threadIdx.x;
    float sx = partials[t];
    float se = partials[NBLK2 + t];
    #pragma unroll
    for (int o = 32; o > 0; o >>= 1) {
        sx += __shfl_down(sx, o);
        se += __shfl_down(se, o);
    }
    int wid = t >> 6, lane = t & 63;
    if (lane == 0) { r1[wid] = sx; r2[wid] = se; }
    __syncthreads();
    if (t == 0) {
        float S = (r1[0] + r1[1]) + (r1[2] + r1[3]);
        float E = (r2[0] + r2[1]) + (r2[2] + r2[3]);
        out[0] = logf(E / (float)BATCH) - S / (float)BATCH;
    }
}

extern "C" void kernel_launch(void* const* d_in, const int* in_sizes, int n_in,
                              void* d_out, int out_size, void* d_ws, size_t ws_size,
                              hipStream_t stream)
{
    const float* x    = (const float*)d_in[0];
    const int*   ij   = (const int*)d_in[1];
    const int*   perm = (const int*)d_in[2];
    const float* cw   = (const float*)d_in[3];
    const float* cb   = (const float*)d_in[4];
    const float* xw1  = (const float*)d_in[5];
    const float* xb1  = (const float*)d_in[6];
    const float* xw2  = (const float*)d_in[7];
    const float* xb2  = (const float*)d_in[8];
    const float* xw3  = (const float*)d_in[9];
    const float* xb3  = (const float*)d_in[10];
    const float* yw1  = (const float*)d_in[11];
    const float* yb1  = (const float*)d_in[12];
    const float* yw2  = (const float*)d_in[13];
    const float* yb2  = (const float*)d_in[14];
    const float* yw3  = (const float*)d_in[15];
    const float* yb3  = (const float*)d_in[16];
    const float* fw   = (const float*)d_in[17];
    const float* fb   = (const float*)d_in[18];

    float* partials = (float*)d_ws;   // 512 floats, fully overwritten each launch

    k_fused<<<NBLK2, 256, 0, stream>>>(x, ij, perm, cw, cb,
                                       xw1, xb1, xw2, xb2, xw3, xb3,
                                       yw1, yb1, yw2, yb2, yw3, yb3,
                                       fw, fb, partials);
    k_final<<<1, 256, 0, stream>>>(partials, (float*)d_out);
}

// Round 12
// 12.082 us; speedup vs baseline: 2.1374x; 1.0079x over previous
//
#include <hip/hip_runtime.h>
#include <math.h>

#define BATCH 4096
#define IMGD 192
#define HC 64
#define PADV 6
#define NBLK2 256      // one block per CU
#define IPB 16         // batch items per block

// padded-weight LDS layout (floats), rows padded to 12 (16B aligned):
//  per-branch block: w1@+0(9x12) w2@+108(9x12) w3@+216(15x12) b1@+396(9) b2@+405(9) b3@+414(15)
//  x-branch @0, y-branch @432; fw@864(15) fb@879 ; total 880
#define XB 0
#define YB 432
#define W1O 0
#define W2O 108
#define W3O 216
#define B1O 396
#define B2O 405
#define B3O 414
#define FWO 864
#define FBO 879

__global__ __launch_bounds__(256) void k_fused(
    const float* __restrict__ x, const int* __restrict__ ij,
    const int* __restrict__ perm,
    const float* __restrict__ cw, const float* __restrict__ cb,
    const float* __restrict__ xw1, const float* __restrict__ xb1,
    const float* __restrict__ xw2, const float* __restrict__ xb2,
    const float* __restrict__ xw3, const float* __restrict__ xb3,
    const float* __restrict__ yw1, const float* __restrict__ yb1,
    const float* __restrict__ yw2, const float* __restrict__ yb2,
    const float* __restrict__ yw3, const float* __restrict__ yb3,
    const float* __restrict__ fw, const float* __restrict__ fb,
    float* __restrict__ partials)  // [0..255]=sum(pred_xy), [256..511]=sum(exp(pred_x_y))
{
    __shared__ __align__(16) float s[880];
    __shared__ int   pidx[IPB];
    __shared__ int2  ij2[2 * IPB];       // [0..15] own (i0,j0), [16..31] permuted
    __shared__ float lpatch[IPB * 27];   // 0..8 p1, 9..17 p2, 18..26 p2s
    __shared__ float bout[48 * 15];

    int t  = threadIdx.x;
    int b0 = blockIdx.x * IPB;

    // ---- dependent index chains FIRST, in-register, split across waves ----
    if (t < IPB) {                        // wave 0: perm -> ij[pb] (the 2-round chain)
        int pb  = perm[b0 + t];
        pidx[t] = pb;
        ij2[IPB + t] = ((const int2*)ij)[pb];
    } else if (t >= 64 && t < 64 + IPB) { // wave 1: own ij (1 round, parallel)
        int item = t - 64;
        ij2[item] = ((const int2*)ij)[b0 + item];
    }

    // ---- weight staging (independent loads; overlap the chains) ----
    for (int i = t; i < 108; i += 256) {
        int row = i / 12, col = i - row * 12;
        if (col < 9) {
            int src = row * 9 + col;
            s[XB + W1O + i] = xw1[src];  s[XB + W2O + i] = xw2[src];
            s[YB + W1O + i] = yw1[src];  s[YB + W2O + i] = yw2[src];
        }
    }
    for (int i = t; i < 180; i += 256) {
        int row = i / 12, col = i - row * 12;
        if (col < 9) {
            int src = row * 9 + col;
            s[XB + W3O + i] = xw3[src];  s[YB + W3O + i] = yw3[src];
        }
    }
    if (t >= 192) {
        int tb = t - 192;
        if (tb < 9)       { s[XB + B1O + tb] = xb1[tb];  s[XB + B2O + tb] = xb2[tb];
                            s[YB + B1O + tb] = yb1[tb];  s[YB + B2O + tb] = yb2[tb]; }
        else if (tb < 24) { int j = tb - 9;  s[XB + B3O + j] = xb3[j];  s[YB + B3O + j] = yb3[j]; }
        else if (tb < 39) { int j = tb - 24; s[FWO + j] = fw[j]; }
        else if (tb == 39){ s[FBO] = fb[0]; }
    }

    float w[9];
    #pragma unroll
    for (int i = 0; i < 9; ++i) w[i] = cw[i];   // uniform -> scalar loads
    float cbias = cb[0];
    __syncthreads();                     // single barrier before gather

    // ---- gather: 2 conv outputs per thread, indices LDS-resident ----
    {
        int idxA = t;
        int itemA = idxA / 27;  int pA = idxA - itemA * 27;
        int rA, cA, selA, slotA;
        if (pA < 18) { rA = pA / 6; cA = pA - rA * 6; selA = 0;
                       int h = (cA >= 3); slotA = h * 9 + rA * 3 + (cA - 3 * h); }
        else         { int q = pA - 18; rA = q / 3; cA = 3 + q - rA * 3; selA = 1; slotA = 18 + q; }
        int bbA = selA ? pidx[itemA] : (b0 + itemA);
        int2 ijA = ij2[selA * IPB + itemA];
        int rrA = ijA.x - PADV + rA;  if (rrA < 0) rrA += HC;
        int ccA = ijA.y - PADV + cA;  if (ccA < 0) ccA += HC;
        const float* pa = x + (size_t)bbA * (IMGD * IMGD) + (size_t)(rrA * 3) * IMGD + ccA * 3;

        bool hasB = (t < 176);
        int idxB = t + 256;
        int itemB = idxB / 27;  int pB = idxB - itemB * 27;
        int rB, cB, selB, slotB;
        if (pB < 18) { rB = pB / 6; cB = pB - rB * 6; selB = 0;
                       int h = (cB >= 3); slotB = h * 9 + rB * 3 + (cB - 3 * h); }
        else         { int q = pB - 18; rB = q / 3; cB = 3 + q - rB * 3; selB = 1; slotB = 18 + q; }
        itemB = hasB ? itemB : 0;
        int bbB = selB ? pidx[itemB] : (b0 + itemB);
        int2 ijB = ij2[selB * IPB + itemB];
        int rrB = ijB.x - PADV + rB;  if (rrB < 0) rrB += HC;
        int ccB = ijB.y - PADV + cB;  if (ccB < 0) ccB += HC;
        const float* pb = hasB ? (x + (size_t)bbB * (IMGD * IMGD) + (size_t)(rrB * 3) * IMGD + ccB * 3)
                               : pa;

        float a0 = pa[0],          a1 = pa[1],            a2 = pa[2];
        float a3 = pa[IMGD],       a4 = pa[IMGD + 1],     a5 = pa[IMGD + 2];
        float a6 = pa[2 * IMGD],   a7 = pa[2 * IMGD + 1], a8 = pa[2 * IMGD + 2];
        float e0 = pb[0],          e1 = pb[1],            e2 = pb[2];
        float e3 = pb[IMGD],       e4 = pb[IMGD + 1],     e5 = pb[IMGD + 2];
        float e6 = pb[2 * IMGD],   e7 = pb[2 * IMGD + 1], e8 = pb[2 * IMGD + 2];

        float vA = cbias + a0*w[0] + a1*w[1] + a2*w[2] + a3*w[3] + a4*w[4]
                         + a5*w[5] + a6*w[6] + a7*w[7] + a8*w[8];
        lpatch[itemA * 27 + slotA] = vA;
        if (hasB) {
            float vB = cbias + e0*w[0] + e1*w[1] + e2*w[2] + e3*w[3] + e4*w[4]
                             + e5*w[5] + e6*w[6] + e7*w[7] + e8*w[8];
            lpatch[itemB * 27 + slotB] = vB;
        }
    }
    __syncthreads();

    // ---- MLP: 3 waves x 16 lanes (branch per wave, broadcast weights) ----
    {
        int wv = t >> 6, l = t & 63;
        if (wv < 3 && l < 16) {
            int woff = (wv == 0) ? XB : YB;
            int ib = wv * 16 + l;
            float p[9];
            #pragma unroll
            for (int k = 0; k < 9; ++k) p[k] = lpatch[l * 27 + wv * 9 + k];

            float v[9];
            #pragma unroll
            for (int j = 0; j < 9; ++j) {
                const float4 r0 = *(const float4*)&s[woff + W1O + j * 12];
                const float4 r1 = *(const float4*)&s[woff + W1O + j * 12 + 4];
                float acc = s[woff + B1O + j]
                    + r0.x*p[0] + r0.y*p[1] + r0.z*p[2] + r0.w*p[3]
                    + r1.x*p[4] + r1.y*p[5] + r1.z*p[6] + r1.w*p[7]
                    + s[woff + W1O + j * 12 + 8] * p[8];
                v[j] = p[j] + fmaxf(acc, 0.0f);
            }
            float u[9];
            #pragma unroll
            for (int j = 0; j < 9; ++j) {
                const float4 r0 = *(const float4*)&s[woff + W2O + j * 12];
                const float4 r1 = *(const float4*)&s[woff + W2O + j * 12 + 4];
                float acc = s[woff + B2O + j]
                    + r0.x*v[0] + r0.y*v[1] + r0.z*v[2] + r0.w*v[3]
                    + r1.x*v[4] + r1.y*v[5] + r1.z*v[6] + r1.w*v[7]
                    + s[woff + W2O + j * 12 + 8] * v[8];
                u[j] = v[j] + fmaxf(acc, 0.0f);
            }
            #pragma unroll
            for (int j = 0; j < 15; ++j) {
                const float4 r0 = *(const float4*)&s[woff + W3O + j * 12];
                const float4 r1 = *(const float4*)&s[woff + W3O + j * 12 + 4];
                float acc = s[woff + B3O + j]
                    + r0.x*u[0] + r0.y*u[1] + r0.z*u[2] + r0.w*u[3]
                    + r1.x*u[4] + r1.y*u[5] + r1.z*u[6] + r1.w*u[7]
                    + s[woff + W3O + j * 12 + 8] * u[8];
                bout[ib * 15 + j] = acc;
            }
        }
    }
    __syncthreads();

    // ---- head + exp + 16-lane reduce ----
    if (t < IPB) {
        float fbv = s[FBO];
        float pxy = fbv, pxs = fbv;
        #pragma unroll
        for (int j = 0; j < 15; ++j) {
            float oxj  = bout[t * 15 + j];
            float oyj  = bout[(16 + t) * 15 + j];
            float oysj = bout[(32 + t) * 15 + j];
            float fwj  = s[FWO + j];
            pxy += fmaxf(oxj + oyj,  0.0f) * fwj;
            pxs += fmaxf(oxj + oysj, 0.0f) * fwj;
        }
        float e = expf(pxs);
        #pragma unroll
        for (int o = 8; o > 0; o >>= 1) {
            pxy += __shfl_down(pxy, o);
            e   += __shfl_down(e, o);
        }
        if (t == 0) {
            partials[blockIdx.x]         = pxy;
            partials[NBLK2 + blockIdx.x] = e;
        }
    }
}

// ---------------- finalize: 1 wave, coalesced float4 reads ----------------
// lane k sums partials {k, k+64, k+128, k+192} for both halves via two
// float4 loads (64 lanes x 2 x 16B = 2KB, perfectly coalesced), then one
// 64-lane butterfly. Fixed-order fp32 -> bit-deterministic.
__global__ __launch_bounds__(64) void k_final(const float* __restrict__ partials,
                                              float* __restrict__ out)
{
    int t = threadIdx.x;
    const float4* p4 = (const float4*)partials;       // 128 float4s total
    float4 a = p4[t];                                 // partials[4t .. 4t+3]   (pred_xy half: t<64)
    float4 b = p4[64 + t];                            // partials[256+4t .. ]   (exp half)
    float sx = (a.x + a.y) + (a.z + a.w);
    float se = (b.x + b.y) + (b.z + b.w);
    #pragma unroll
    for (int o = 32; o > 0; o >>= 1) {
        sx += __shfl_down(sx, o);
        se += __shfl_down(se, o);
    }
    if (t == 0) out[0] = logf(se / (float)BATCH) - sx / (float)BATCH;
}

extern "C" void kernel_launch(void* const* d_in, const int* in_sizes, int n_in,
                              void* d_out, int out_size, void* d_ws, size_t ws_size,
                              hipStream_t stream)
{
    const float* x    = (const float*)d_in[0];
    const int*   ij   = (const int*)d_in[1];
    const int*   perm = (const int*)d_in[2];
    const float* cw   = (const float*)d_in[3];
    const float* cb   = (const float*)d_in[4];
    const float* xw1  = (const float*)d_in[5];
    const float* xb1  = (const float*)d_in[6];
    const float* xw2  = (const float*)d_in[7];
    const float* xb2  = (const float*)d_in[8];
    const float* xw3  = (const float*)d_in[9];
    const float* xb3  = (const float*)d_in[10];
    const float* yw1  = (const float*)d_in[11];
    const float* yb1  = (const float*)d_in[12];
    const float* yw2  = (const float*)d_in[13];
    const float* yb2  = (const float*)d_in[14];
    const float* yw3  = (const float*)d_in[15];
    const float* yb3  = (const float*)d_in[16];
    const float* fw   = (const float*)d_in[17];
    const float* fb   = (const float*)d_in[18];

    float* partials = (float*)d_ws;   // 512 floats, fully overwritten each launch

    k_fused<<<NBLK2, 256, 0, stream>>>(x, ij, perm, cw, cb,
                                       xw1, xb1, xw2, xb2, xw3, xb3,
                                       yw1, yb1, yw2, yb2, yw3, yb3,
                                       fw, fb, partials);
    k_final<<<1, 64, 0, stream>>>(partials, (float*)d_out);
}